// Round 1
// baseline (11073.077 us; speedup 1.0000x reference)
//
#include <hip/hip_runtime.h>

namespace {
constexpr int B_    = 8;
constexpr int NT_   = 256;
constexpr int NX_   = 256;
constexpr int NREC_ = 64;
constexpr float DT2  = 1e-6f;   // DT*DT
constexpr float KLAP = 1e-8f;   // DT*DT/(DH*DH)
constexpr int RCAP = 6;

// binary-tree select of h[idx>>3][idx&7] for runtime idx (63 cndmask, no scratch)
__device__ __forceinline__ float select64f(const float (&h)[8][8], int idx) {
    float v32[32];
#pragma unroll
    for (int k = 0; k < 32; ++k) {
        float a = h[(2*k)>>3][(2*k)&7];
        float b = h[(2*k+1)>>3][(2*k+1)&7];
        v32[k] = (idx & 1) ? b : a;
    }
    float v16[16];
#pragma unroll
    for (int k = 0; k < 16; ++k) v16[k] = (idx & 2) ? v32[2*k+1] : v32[2*k];
    float v8[8];
#pragma unroll
    for (int k = 0; k < 8; ++k)  v8[k]  = (idx & 4) ? v16[2*k+1] : v16[2*k];
    float v4[4];
#pragma unroll
    for (int k = 0; k < 4; ++k)  v4[k]  = (idx & 8) ? v8[2*k+1]  : v8[2*k];
    float v2[2];
#pragma unroll
    for (int k = 0; k < 2; ++k)  v2[k]  = (idx & 16) ? v4[2*k+1] : v4[2*k];
    return (idx & 32) ? v2[1] : v2[0];
}
} // namespace

// One block per batch. 1024 threads = 32x32 tiles of 8x8 cells (256x256 grid).
// Wave = 2 tile-rows x 32 tile-cols: horizontal halos + intra-wave vertical
// halos via __shfl; wave-crossing vertical halos via 32KB LDS (2 barriers/step).
extern "C" __global__ __launch_bounds__(1024, 1)
void wave_leapfrog_kernel(const float* __restrict__ x,
                          const float* __restrict__ vp,
                          const int* __restrict__ src_loc,
                          const int* __restrict__ rec_loc,
                          float* __restrict__ out)
{
    __shared__ float pub[32][32][8];       // 32 KB vertical halo exchange
    __shared__ float wav[NT_];             // 1 KB source wavelet
    __shared__ int   rtab[1024][RCAP];     // 24 KB receiver->thread table

    const int b    = blockIdx.x;
    const int tid  = threadIdx.x;
    const int tx   = tid & 31;             // tile col 0..31
    const int ty   = tid >> 5;             // tile row 0..31
    const int lane = tid & 63;
    const int r0   = ty << 3;
    const int c0   = tx << 3;

    if (tid < NT_) wav[tid] = x[b * NT_ + tid];

    // coef = vp^2*DT^2/DH^2 ; am = 2 - 4*coef  (5 VALU ops/cell update)
    float coef[8][8], am[8][8];
#pragma unroll
    for (int i = 0; i < 8; ++i) {
        const float4* vrow = (const float4*)&vp[(r0 + i) * NX_ + c0];
        float4 a4 = vrow[0], b4 = vrow[1];
        float vv[8] = {a4.x,a4.y,a4.z,a4.w,b4.x,b4.y,b4.z,b4.w};
#pragma unroll
        for (int j = 0; j < 8; ++j) {
            float c = vv[j] * vv[j] * KLAP;
            coef[i][j] = c;
            am[i][j]   = 2.0f - 4.0f * c;
        }
    }

    const int sz = src_loc[b*2+0], sx = src_loc[b*2+1];
    const bool has_src = ((sz >> 3) == ty) && ((sx >> 3) == tx);
    const int si = sz & 7, sj = sx & 7;

    int rcnt = 0;
#pragma unroll 1
    for (int r = 0; r < NREC_; ++r) {
        int rz = rec_loc[(b*NREC_ + r)*2 + 0];
        int rx = rec_loc[(b*NREC_ + r)*2 + 1];
        if (((rz >> 3) == ty) && ((rx >> 3) == tx)) {
            if (rcnt < RCAP) rtab[tid][rcnt] = (r << 6) | ((rz & 7) << 3) | (rx & 7);
            ++rcnt;
        }
    }
    if (rcnt > RCAP) rcnt = RCAP;

    float hA[8][8], hB[8][8];
#pragma unroll
    for (int i = 0; i < 8; ++i)
#pragma unroll
        for (int j = 0; j < 8; ++j) { hA[i][j] = 0.f; hB[i][j] = 0.f; }

    float* outb = out + b * (NT_ * NREC_);

    auto step = [&](float (&h1)[8][8], float (&h2)[8][8], int t) {
        // publish wave-crossing vertical halo row: even ty -> its top row
        // (needed by odd tile above in wave w-1); odd ty -> its bottom row.
        {
            float4 p0, p1;
            if (ty & 1) { p0 = make_float4(h1[7][0],h1[7][1],h1[7][2],h1[7][3]);
                          p1 = make_float4(h1[7][4],h1[7][5],h1[7][6],h1[7][7]); }
            else        { p0 = make_float4(h1[0][0],h1[0][1],h1[0][2],h1[0][3]);
                          p1 = make_float4(h1[0][4],h1[0][5],h1[0][6],h1[0][7]); }
            float4* d = (float4*)&pub[ty][tx][0];
            d[0] = p0; d[1] = p1;
        }
        __syncthreads();

        float nn[8], ss[8], ww[8], ee[8];
        {
            const bool odd   = (ty & 1) != 0;
            const bool valid = odd ? (ty < 31) : (ty > 0);
            const int  oy    = odd ? (ty + 1) : (ty - 1);
            const int  cy    = valid ? oy : ty;     // safe dummy read when at edge
            const float4* s4 = (const float4*)&pub[cy][tx][0];
            float4 q0 = s4[0], q1 = s4[1];
            float other[8] = {q0.x,q0.y,q0.z,q0.w,q1.x,q1.y,q1.z,q1.w};
#pragma unroll
            for (int j = 0; j < 8; ++j) if (!valid) other[j] = 0.f;
#pragma unroll
            for (int j = 0; j < 8; ++j) {
                // intra-wave vertical halo: partner lane is lane^32
                float contrib = (lane < 32) ? h1[7][j] : h1[0][j];
                float got = __shfl_xor(contrib, 32, 64);
                nn[j] = odd ? got   : other[j];
                ss[j] = odd ? other[j] : got;
            }
        }
#pragma unroll
        for (int i = 0; i < 8; ++i) {
            float wv = __shfl_up(h1[i][7], 1, 64);
            float ev = __shfl_down(h1[i][0], 1, 64);
            ww[i] = (tx == 0)  ? 0.f : wv;
            ee[i] = (tx == 31) ? 0.f : ev;
        }

        // hn = (2-4c)*h1 - h2 + c*(n+s+w+e), written in place over h2
#pragma unroll
        for (int i = 0; i < 8; ++i) {
#pragma unroll
            for (int j = 0; j < 8; ++j) {
                float n = (i > 0) ? h1[i-1][j] : nn[j];
                float s = (i < 7) ? h1[i+1][j] : ss[j];
                float w = (j > 0) ? h1[i][j-1] : ww[i];
                float e = (j < 7) ? h1[i][j+1] : ee[i];
                float sum = (n + s) + (w + e);
                float r2  = fmaf(am[i][j], h1[i][j], -h2[i][j]);
                h2[i][j]  = fmaf(coef[i][j], sum, r2);
            }
        }

        // global Dirichlet boundary stays exactly 0 (reference zeroes the lap there)
        if (ty == 0)  {
#pragma unroll
            for (int j = 0; j < 8; ++j) h2[0][j] = 0.f; }
        if (ty == 31) {
#pragma unroll
            for (int j = 0; j < 8; ++j) h2[7][j] = 0.f; }
        if (tx == 0)  {
#pragma unroll
            for (int i = 0; i < 8; ++i) h2[i][0] = 0.f; }
        if (tx == 31) {
#pragma unroll
            for (int i = 0; i < 8; ++i) h2[i][7] = 0.f; }

        // source injection (before receiver gather, matching reference order)
        if (has_src) {
            float v = DT2 * wav[t];
#pragma unroll
            for (int i = 0; i < 8; ++i) if (si == i) {
#pragma unroll
                for (int j = 0; j < 8; ++j) if (sj == j) h2[i][j] += v;
            }
        }

        // receiver gather
#pragma unroll 1
        for (int k = 0; k < rcnt; ++k) {
            int p   = rtab[tid][k];
            int rid = p >> 6;
            float v = select64f(h2, p & 63);
            outb[t * NREC_ + rid] = v;
        }
        __syncthreads();   // protect pub before next step's publish
    };

#pragma unroll 1
    for (int t = 0; t < NT_; t += 2) {
        step(hA, hB, t);
        step(hB, hA, t + 1);
    }
}

extern "C" void kernel_launch(void* const* d_in, const int* in_sizes, int n_in,
                              void* d_out, int out_size, void* d_ws, size_t ws_size,
                              hipStream_t stream) {
    const float* x   = (const float*)d_in[0];
    const float* vp  = (const float*)d_in[1];
    const int*   src = (const int*)d_in[2];
    const int*   rec = (const int*)d_in[3];
    float*       o   = (float*)d_out;
    hipLaunchKernelGGL(wave_leapfrog_kernel, dim3(B_), dim3(1024), 0, stream,
                       x, vp, src, rec, o);
}

// Round 2
// 1163.546 us; speedup vs baseline: 9.5167x; 9.5167x over previous
//
#include <hip/hip_runtime.h>

namespace {
constexpr int B_     = 8;
constexpr int NT_    = 256;
constexpr int NZ_    = 256;
constexpr int NX_    = 256;
constexpr int NREC_  = 64;
constexpr int PIECES = 8;             // blocks per batch (vertical strips)
constexpr int ROWS   = NZ_ / PIECES;  // 32 rows per block
constexpr float DT2  = 1e-6f;         // DT*DT
constexpr float KLAP = 1e-8f;         // DT*DT/(DH*DH)
constexpr size_t HALO_BYTE_OFF = 4096;

// 3-level cndmask tree: h[idx] for runtime idx in [0,8), no scratch
__device__ __forceinline__ float select8(const float (&h)[8], int idx) {
    float a0 = (idx & 1) ? h[1] : h[0];
    float a1 = (idx & 1) ? h[3] : h[2];
    float a2 = (idx & 1) ? h[5] : h[4];
    float a3 = (idx & 1) ? h[7] : h[6];
    float b0 = (idx & 2) ? a1 : a0;
    float b1 = (idx & 2) ? a3 : a2;
    return (idx & 4) ? b1 : b0;
}

__device__ __forceinline__ void st_agent(float* p, float v) {
    __hip_atomic_store(p, v, __ATOMIC_RELAXED, __HIP_MEMORY_SCOPE_AGENT);
}
__device__ __forceinline__ float ld_agent(const float* p) {
    return __hip_atomic_load(p, __ATOMIC_RELAXED, __HIP_MEMORY_SCOPE_AGENT);
}
} // namespace

// 64 blocks: piece p (0..7 vertical strip) of batch b. blockIdx = p*8 + b so
// all pieces of one batch share an XCD (blockIdx%8 round-robin) for fast
// halo/flag traffic. Each thread owns 1 row x 8 cols in registers.
// Vertical halo: LDS publish (intra-block) + global rows w/ flags (cross-block).
extern "C" __global__ __launch_bounds__(1024, 4)
void wave_fd_kernel(const float* __restrict__ x,
                    const float* __restrict__ vp,
                    const int* __restrict__ src_loc,
                    const int* __restrict__ rec_loc,
                    float* __restrict__ out,
                    int* __restrict__ flags,     // [64 blocks][2] seq counters
                    float* __restrict__ halo)    // [64][buf=2][top/bot=2][256]
{
    __shared__ float pub[ROWS][32][8];   // 32 KB intra-block vertical halo
    __shared__ float wav[NT_];           // 1 KB wavelet

    const int bid = blockIdx.x;
    const int b   = bid & 7;             // batch  -> XCD (blockIdx % 8)
    const int p   = bid >> 3;            // piece within batch
    const int blk = b * PIECES + p;      // logical block id for halo/flag slots
    const int tid = threadIdx.x;
    const int tx  = tid & 31;            // 8-col group 0..31
    const int ty  = tid >> 5;            // row within strip 0..31
    const int grow = p * ROWS + ty;      // global row owned by this thread
    const int gc0  = tx << 3;            // first global col owned

    if (tid < NT_) wav[tid] = x[b * NT_ + tid];

    // per-cell constants: cf = vp^2*DT^2/DH^2, am = 2 - 4*cf
    float cf[8], am[8];
    {
        const float4* v4 = (const float4*)&vp[grow * NX_ + gc0];
        float4 q0 = v4[0], q1 = v4[1];
        float vv[8] = {q0.x,q0.y,q0.z,q0.w,q1.x,q1.y,q1.z,q1.w};
#pragma unroll
        for (int j = 0; j < 8; ++j) {
            float c = vv[j] * vv[j] * KLAP;
            cf[j] = c;
            am[j] = 2.0f - 4.0f * c;
        }
    }

    const int sz = src_loc[b*2+0], sx = src_loc[b*2+1];
    const bool has_src = (sz == grow) && ((sx >> 3) == tx);
    const int  sj = sx & 7;

    // receiver ownership (scalars, not array -> no scratch)
    int rt0 = 0, rt1 = 0, rt2 = 0, rt3 = 0, rcnt = 0;
#pragma unroll 1
    for (int r = 0; r < NREC_; ++r) {
        int rz = rec_loc[(b*NREC_ + r)*2 + 0];
        int rx = rec_loc[(b*NREC_ + r)*2 + 1];
        if (rz == grow && (rx >> 3) == tx) {
            int pk = (r << 3) | (rx & 7);
            if      (rcnt == 0) rt0 = pk;
            else if (rcnt == 1) rt1 = pk;
            else if (rcnt == 2) rt2 = pk;
            else if (rcnt == 3) rt3 = pk;
            ++rcnt;
        }
    }

    float hA[8], hB[8];
#pragma unroll
    for (int j = 0; j < 8; ++j) { hA[j] = 0.f; hB[j] = 0.f; }

    float* outb = out + b * (NT_ * NREC_);

    // halo slot helpers: slot(blk,buf,which) base in floats
    auto hptr = [&](int bk, int buf, int which) -> float* {
        return halo + (size_t)(((bk * 2 + buf) * 2 + which)) * NX_;
    };

    auto step = [&](float (&h1)[8], float (&h2)[8], int t) {
        const int buf = t & 1;
        // --- publish h1: LDS (all) + global rows (strip boundaries) ---
        *(float4*)&pub[ty][tx][0] = make_float4(h1[0],h1[1],h1[2],h1[3]);
        *(float4*)&pub[ty][tx][4] = make_float4(h1[4],h1[5],h1[6],h1[7]);
        if (ty == 0 && p > 0) {                    // wave 0, lanes 0..31
            float* d = hptr(blk, buf, 0) + gc0;
#pragma unroll
            for (int j = 0; j < 8; ++j) st_agent(&d[j], h1[j]);
            if (tx == 0)
                __hip_atomic_store(&flags[blk*2+0], t+1, __ATOMIC_RELEASE,
                                   __HIP_MEMORY_SCOPE_AGENT);
        }
        if (ty == ROWS-1 && p < PIECES-1) {        // wave 15, lanes 32..63
            float* d = hptr(blk, buf, 1) + gc0;
#pragma unroll
            for (int j = 0; j < 8; ++j) st_agent(&d[j], h1[j]);
            if (tx == 0)
                __hip_atomic_store(&flags[blk*2+1], t+1, __ATOMIC_RELEASE,
                                   __HIP_MEMORY_SCOPE_AGENT);
        }
        __syncthreads();

        // --- gather north/south rows ---
        float nn[8], ss[8];
        if (ty > 0) {
            float4 q0 = *(const float4*)&pub[ty-1][tx][0];
            float4 q1 = *(const float4*)&pub[ty-1][tx][4];
            nn[0]=q0.x; nn[1]=q0.y; nn[2]=q0.z; nn[3]=q0.w;
            nn[4]=q1.x; nn[5]=q1.y; nn[6]=q1.z; nn[7]=q1.w;
        } else if (p > 0) {
            const int nb = blk - 1;
            while (__hip_atomic_load(&flags[nb*2+1], __ATOMIC_ACQUIRE,
                                     __HIP_MEMORY_SCOPE_AGENT) < t+1)
                __builtin_amdgcn_s_sleep(2);
            const float* s = hptr(nb, buf, 1) + gc0;
#pragma unroll
            for (int j = 0; j < 8; ++j) nn[j] = ld_agent(&s[j]);
        } else {
#pragma unroll
            for (int j = 0; j < 8; ++j) nn[j] = 0.f;
        }
        if (ty < ROWS-1) {
            float4 q0 = *(const float4*)&pub[ty+1][tx][0];
            float4 q1 = *(const float4*)&pub[ty+1][tx][4];
            ss[0]=q0.x; ss[1]=q0.y; ss[2]=q0.z; ss[3]=q0.w;
            ss[4]=q1.x; ss[5]=q1.y; ss[6]=q1.z; ss[7]=q1.w;
        } else if (p < PIECES-1) {
            const int sb = blk + 1;
            while (__hip_atomic_load(&flags[sb*2+0], __ATOMIC_ACQUIRE,
                                     __HIP_MEMORY_SCOPE_AGENT) < t+1)
                __builtin_amdgcn_s_sleep(2);
            const float* s = hptr(sb, buf, 0) + gc0;
#pragma unroll
            for (int j = 0; j < 8; ++j) ss[j] = ld_agent(&s[j]);
        } else {
#pragma unroll
            for (int j = 0; j < 8; ++j) ss[j] = 0.f;
        }

        // --- horizontal halo via shuffle (same wave, same row half) ---
        float wv = __shfl_up(h1[7], 1, 64);
        float ev = __shfl_down(h1[0], 1, 64);
        float ww = (tx == 0)  ? 0.f : wv;
        float ee = (tx == 31) ? 0.f : ev;

        // --- update: hn = (2-4c)h1 - h2 + c*(n+s+w+e) ---
#pragma unroll
        for (int j = 0; j < 8; ++j) {
            float n = nn[j], s = ss[j];
            float w = (j > 0) ? h1[j-1] : ww;
            float e = (j < 7) ? h1[j+1] : ee;
            float sum = (n + s) + (w + e);
            h2[j] = fmaf(cf[j], sum, fmaf(am[j], h1[j], -h2[j]));
        }
        // Dirichlet boundary rows/cols stay exactly 0
        if (grow == 0 || grow == NZ_-1) {
#pragma unroll
            for (int j = 0; j < 8; ++j) h2[j] = 0.f;
        }
        if (tx == 0)  h2[0] = 0.f;
        if (tx == 31) h2[7] = 0.f;

        // source injection (static-index guard, no scratch)
        if (has_src) {
            float v = DT2 * wav[t];
#pragma unroll
            for (int j = 0; j < 8; ++j) if (j == sj) h2[j] += v;
        }

        // receiver gather
        if (rcnt > 0) outb[t*NREC_ + (rt0 >> 3)] = select8(h2, rt0 & 7);
        if (rcnt > 1) outb[t*NREC_ + (rt1 >> 3)] = select8(h2, rt1 & 7);
        if (rcnt > 2) outb[t*NREC_ + (rt2 >> 3)] = select8(h2, rt2 & 7);
        if (rcnt > 3) outb[t*NREC_ + (rt3 >> 3)] = select8(h2, rt3 & 7);

        __syncthreads();   // protect pub (WAR) before next step's publish
    };

#pragma unroll 1
    for (int t = 0; t < NT_; t += 2) {
        step(hA, hB, t);
        step(hB, hA, t + 1);
    }
}

extern "C" void kernel_launch(void* const* d_in, const int* in_sizes, int n_in,
                              void* d_out, int out_size, void* d_ws, size_t ws_size,
                              hipStream_t stream) {
    const float* x   = (const float*)d_in[0];
    const float* vp  = (const float*)d_in[1];
    const int*   src = (const int*)d_in[2];
    const int*   rec = (const int*)d_in[3];
    float*       o   = (float*)d_out;
    int*   flags = (int*)d_ws;
    float* halo  = (float*)((char*)d_ws + HALO_BYTE_OFF);
    // zero the flag region (d_ws is poisoned 0xAA before every launch)
    hipMemsetAsync(d_ws, 0, HALO_BYTE_OFF, stream);
    hipLaunchKernelGGL(wave_fd_kernel, dim3(B_ * PIECES), dim3(1024), 0, stream,
                       x, vp, src, rec, o, flags, halo);
}